// Round 3
// baseline (486.328 us; speedup 1.0000x reference)
//
#include <hip/hip_runtime.h>
#include <hip/hip_bf16.h>
#include <stdint.h>

#define NCAT 32
#define DIN  1536
#define DMID 1024
#define NB   128
#define TT   32

#define BM 128
#define BN 64
#define BK 32
#define LDA 40   // ushort stride for A tile rows (padded, 16B-aligned, ~2-way banks = free)
#define MAXG 56  // 8 residues x 7 slots; sum ceil(n_c/4) <= 56 always fits

typedef __attribute__((ext_vector_type(8))) short short8;
typedef __attribute__((ext_vector_type(4))) float f32x4;

static __device__ __forceinline__ unsigned int pk2bf(float lo, float hi) {
  unsigned short a = __builtin_bit_cast(unsigned short, __float2bfloat16(lo));
  unsigned short b = __builtin_bit_cast(unsigned short, __float2bfloat16(hi));
  return ((unsigned int)b << 16) | (unsigned int)a;
}

// Raw barrier WITHOUT vmcnt drain: only LDS ops must be visible across it.
// __syncthreads() would emit s_waitcnt vmcnt(0) and kill the global-load pipeline.
static __device__ __forceinline__ void bar_noflush() {
  asm volatile("s_waitcnt lgkmcnt(0)" ::: "memory");
  __builtin_amdgcn_s_barrier();
  asm volatile("" ::: "memory");
}

// ws int layout: [0..127] batch_list sorted by category; [128] = MAXG;
// [132 + 4s ..] = {cat, start, cnt, pad} for slot s in [0,56). cnt==0 => empty.
// Slot s runs on XCD (s % 8); same-category groups share a residue so their
// weight reads hit the same L2. hidden bf16 at byte offset 8192.
__global__ void build_groups(const int* __restrict__ cat_ids, int* __restrict__ wsi) {
  __shared__ int cats[NB];
  __shared__ int cnt[NCAT];
  __shared__ int off[NCAT];
  int t = threadIdx.x; // blockDim = 128
  cats[t] = cat_ids[t];
  __syncthreads();
  if (t < NCAT) {
    int n = 0;
    for (int b = 0; b < NB; b++) n += (cats[b] == t);
    cnt[t] = n;
  }
  __syncthreads();
  if (t == 0) {
    int acc = 0;
    for (int c = 0; c < NCAT; c++) { off[c] = acc; acc += cnt[c]; }
  }
  __syncthreads();
  if (t < NCAT) {
    int o = off[t];
    for (int b = 0; b < NB; b++)
      if (cats[b] == t) wsi[o++] = b;
  }
  if (t == 0) {
    for (int s = 0; s < MAXG; s++) {
      wsi[132 + s * 4 + 0] = 0;
      wsi[132 + s * 4 + 1] = 0;
      wsi[132 + s * 4 + 2] = 0;
    }
    int rload[8];
    for (int r = 0; r < 8; r++) rload[r] = 0;
    for (int c = 0; c < NCAT; c++) {
      int n = cnt[c];
      if (n == 0) continue;
      int o = off[c];
      int r = 0;
      for (int k = 1; k < 8; k++) if (rload[k] < rload[r]) r = k;
      for (int j = 0; j < n; j += 4) {
        if (rload[r] >= 7) {
          r = 0;
          for (int k = 1; k < 8; k++) if (rload[k] < rload[r]) r = k;
        }
        int s = r + 8 * rload[r];
        rload[r]++;
        wsi[132 + s * 4 + 0] = c;
        wsi[132 + s * 4 + 1] = o + j;
        wsi[132 + s * 4 + 2] = (n - j) < 4 ? (n - j) : 4;
      }
    }
    wsi[128] = MAXG;
  }
}

// LAYER 1: Ain = x (fp32, rows [batch*32+t][K=1536]), Out = hidden bf16 [4096][1024], relu
// LAYER 2: Ain = hidden (bf16 [4096][1024]), Out = final fp32 [4096][1024]
template <int LAYER>
__global__ __launch_bounds__(256)
void mlp_gemm(const void* __restrict__ Ain, const float* __restrict__ W,
              const float* __restrict__ bias, const int* __restrict__ wsi,
              void* __restrict__ Out, int K) {
  // XCD-aware remap: the 16 column-blocks of one slot land on a single XCD so
  // the shared A-tile and the cat's weight stream are L2 hits.
  const int l    = blockIdx.y * 16 + blockIdx.x;   // gridDim.x == 16
  const int xcd  = l & 7;
  const int m    = l >> 3;                          // 0..111
  const int slot = xcd + 8 * (m >> 4);              // slot % 8 == xcd
  const int cat   = wsi[132 + slot * 4 + 0];
  const int start = wsi[132 + slot * 4 + 1];
  const int cnt   = wsi[132 + slot * 4 + 2];
  if (cnt == 0) return;
  const int n0 = (m & 15) * BN;

  __shared__ unsigned short As[2][BM * LDA];    // 2 x 10240 B
  __shared__ unsigned short Bs[2][4 * BN * 8];  // 2 x 4096 B   (total 28.6 KB)

  const int tid  = threadIdx.x;
  const int lane = tid & 63;
  const int w    = tid >> 6;   // wave id 0..3

  // ---- A staging: thread -> (row = tid>>1, khalf = (tid&1)*16)
  const int arow  = tid >> 1;
  const int khalf = (tid & 1) * 16;
  const int lb    = arow >> 5;
  const int tok   = arow & 31;
  const int lbc   = lb < (cnt - 1) ? lb : (cnt - 1);
  const int batch = wsi[start + lbc];
  const long grow = (long)(batch * TT + tok);

  // ---- B staging: thread -> kc = w (k rows w*8..w*8+7), col = lane
  const float* Wcol = W + (size_t)cat * (size_t)K * 1024 + n0 + lane;

  f32x4 acc[4][2];
#pragma unroll
  for (int i = 0; i < 4; i++)
#pragma unroll
    for (int j = 0; j < 2; j++) acc[i][j] = (f32x4){0.f, 0.f, 0.f, 0.f};

  const int wm  = (w >> 1) * 64;
  const int wn  = (w & 1) * 32;
  const int kg  = lane >> 4;    // 0..3
  const int c16 = lane & 15;

  auto load_tile = [&](int k0, float4 ar[4], uint4 ah[2], float br[8]) {
    if constexpr (LAYER == 1) {
      const float* ap = (const float*)Ain + grow * (long)K + k0 + khalf;
      ar[0] = *(const float4*)(ap + 0);
      ar[1] = *(const float4*)(ap + 4);
      ar[2] = *(const float4*)(ap + 8);
      ar[3] = *(const float4*)(ap + 12);
    } else {
      const uint4* ap = (const uint4*)((const unsigned short*)Ain + grow * (long)K + k0 + khalf);
      ah[0] = ap[0];
      ah[1] = ap[1];
    }
    const float* bp = Wcol + (size_t)(k0 + w * 8) * 1024;
#pragma unroll
    for (int r = 0; r < 8; r++) br[r] = bp[(size_t)r * 1024];
  };

  auto store_tile = [&](int buf, const float4 ar[4], const uint4 ah[2], const float br[8]) {
    if constexpr (LAYER == 1) {
      uint4 aw0 = make_uint4(pk2bf(ar[0].x, ar[0].y), pk2bf(ar[0].z, ar[0].w),
                             pk2bf(ar[1].x, ar[1].y), pk2bf(ar[1].z, ar[1].w));
      uint4 aw1 = make_uint4(pk2bf(ar[2].x, ar[2].y), pk2bf(ar[2].z, ar[2].w),
                             pk2bf(ar[3].x, ar[3].y), pk2bf(ar[3].z, ar[3].w));
      *(uint4*)&As[buf][arow * LDA + khalf]     = aw0;
      *(uint4*)&As[buf][arow * LDA + khalf + 8] = aw1;
    } else {
      *(uint4*)&As[buf][arow * LDA + khalf]     = ah[0];
      *(uint4*)&As[buf][arow * LDA + khalf + 8] = ah[1];
    }
    uint4 bw = make_uint4(pk2bf(br[0], br[1]), pk2bf(br[2], br[3]),
                          pk2bf(br[4], br[5]), pk2bf(br[6], br[7]));
    *(uint4*)&Bs[buf][(w * BN + lane) * 8] = bw;
  };

  auto compute = [&](int buf) {
    short8 afrag[4], bfrag[2];
#pragma unroll
    for (int i = 0; i < 4; i++)
      afrag[i] = *(const short8*)&As[buf][(wm + i * 16 + c16) * LDA + kg * 8];
#pragma unroll
    for (int j = 0; j < 2; j++)
      bfrag[j] = *(const short8*)&Bs[buf][(kg * BN + wn + j * 16 + c16) * 8];
#pragma unroll
    for (int i = 0; i < 4; i++)
#pragma unroll
      for (int j = 0; j < 2; j++)
        acc[i][j] = __builtin_amdgcn_mfma_f32_16x16x32_bf16(afrag[i], bfrag[j], acc[i][j], 0, 0, 0);
  };

  // Two static register sets (no copies -> compiler emits COUNTED vmcnt waits,
  // newest tile's loads stay in flight across the raw barrier).
  float4 arA[4]; uint4 ahA[2]; float brA[8];
  float4 arB[4]; uint4 ahB[2]; float brB[8];

  const int nt = K / BK;   // 48 or 32 (even)

  // prologue: tile0 -> regsA -> LDS0; tile1 -> regsB (left in flight)
  load_tile(0, arA, ahA, brA);
  load_tile(BK, arB, ahB, brB);
  store_tile(0, arA, ahA, brA);   // waits only on regsA's loads
  bar_noflush();

  for (int t = 0; t + 2 <= nt; t += 2) {
    // even step: compute tile t (buf0); store tile t+1 (regsB) -> buf1;
    // prefetch tile t+2 into regsA.
    if (t + 2 < nt) load_tile((t + 2) * BK, arA, ahA, brA);
    store_tile(1, arB, ahB, brB);
    compute(0);
    bar_noflush();

    // odd step: compute tile t+1 (buf1); store tile t+2 (regsA) -> buf0;
    // prefetch tile t+3 into regsB.
    if (t + 3 < nt) load_tile((t + 3) * BK, arB, ahB, brB);
    if (t + 2 < nt) store_tile(0, arA, ahA, brA);
    compute(1);
    bar_noflush();
  }

  // ---------- epilogue ----------
  const int rquad = (lane >> 4) * 4;
#pragma unroll
  for (int i = 0; i < 4; i++) {
#pragma unroll
    for (int j = 0; j < 2; j++) {
      int gcol = n0 + wn + j * 16 + c16;
      float bb = bias[cat * 1024 + gcol];
#pragma unroll
      for (int r = 0; r < 4; r++) {
        int lrow = wm + i * 16 + rquad + r;
        int lb2 = lrow >> 5;
        if (lb2 < cnt) {
          int b2 = wsi[start + lb2];
          long orow = (long)(b2 * TT + (lrow & 31));
          float v = acc[i][j][r] + bb;
          if constexpr (LAYER == 1) {
            v = fmaxf(v, 0.f);
            ((unsigned short*)Out)[orow * DMID + gcol] =
                __builtin_bit_cast(unsigned short, __float2bfloat16(v));
          } else {
            ((float*)Out)[orow * 1024 + gcol] = v;
          }
        }
      }
    }
  }
}

extern "C" void kernel_launch(void* const* d_in, const int* in_sizes, int n_in,
                              void* d_out, int out_size, void* d_ws, size_t ws_size,
                              hipStream_t stream) {
  const float* x       = (const float*)d_in[0];
  const int*   cat_ids = (const int*)d_in[1];
  const float* W1      = (const float*)d_in[2];
  const float* b1      = (const float*)d_in[3];
  const float* W2      = (const float*)d_in[4];
  const float* b2      = (const float*)d_in[5];
  float* out = (float*)d_out;

  int* wsi = (int*)d_ws;
  unsigned short* hidden = (unsigned short*)((char*)d_ws + 8192);

  build_groups<<<dim3(1), dim3(128), 0, stream>>>(cat_ids, wsi);
  mlp_gemm<1><<<dim3(1024 / BN, MAXG), dim3(256), 0, stream>>>(
      (const void*)x, W1, b1, wsi, (void*)hidden, DIN);
  mlp_gemm<2><<<dim3(1024 / BN, MAXG), dim3(256), 0, stream>>>(
      (const void*)hidden, W2, b2, wsi, (void*)out, DMID);
}

// Round 4
// 438.647 us; speedup vs baseline: 1.1087x; 1.1087x over previous
//
#include <hip/hip_runtime.h>
#include <hip/hip_bf16.h>
#include <stdint.h>

#define NCAT 32
#define DIN  1536
#define DMID 1024
#define NB   128
#define TT   32

#define BM 128
#define BN 64
#define BK 32
#define MAXG 56  // 8 residues x 7 slots; sum ceil(n_c/4) <= 56 always fits

typedef __attribute__((ext_vector_type(8))) short short8;
typedef __attribute__((ext_vector_type(4))) float f32x4;

static __device__ __forceinline__ unsigned int pk2bf(float lo, float hi) {
  unsigned short a = __builtin_bit_cast(unsigned short, __float2bfloat16(lo));
  unsigned short b = __builtin_bit_cast(unsigned short, __float2bfloat16(hi));
  return ((unsigned int)b << 16) | (unsigned int)a;
}

// RNE fp32->bf16 pair pack (same numerics as __float2bfloat16).
static __device__ __forceinline__ unsigned int cvtpk(float lo, float hi) {
  unsigned int r;
  asm volatile("v_cvt_pk_bf16_f32 %0, %1, %2" : "=v"(r) : "v"(lo), "v"(hi));
  return r;
}

// async global->LDS DMA, 16B per lane. LDS dest = wave-uniform base + lane*16.
static __device__ __forceinline__ void dma16(const void* g, void* l) {
  __builtin_amdgcn_global_load_lds((const __attribute__((address_space(1))) void*)g,
                                   (__attribute__((address_space(3))) void*)l, 16, 0, 0);
}

// ws int layout: [0..127] batch_list sorted by category; [128] = MAXG;
// [132 + 4s ..] = {cat, start, cnt, pad} for slot s in [0,56). cnt==0 => empty.
// Slot s runs on XCD (s % 8); same-category groups share a residue so their
// weight reads hit the same L2. hidden bf16 at byte offset 8192.
__global__ void build_groups(const int* __restrict__ cat_ids, int* __restrict__ wsi) {
  __shared__ int cats[NB];
  __shared__ int cnt[NCAT];
  __shared__ int off[NCAT];
  int t = threadIdx.x; // blockDim = 128
  cats[t] = cat_ids[t];
  __syncthreads();
  if (t < NCAT) {
    int n = 0;
    for (int b = 0; b < NB; b++) n += (cats[b] == t);
    cnt[t] = n;
  }
  __syncthreads();
  if (t == 0) {
    int acc = 0;
    for (int c = 0; c < NCAT; c++) { off[c] = acc; acc += cnt[c]; }
  }
  __syncthreads();
  if (t < NCAT) {
    int o = off[t];
    for (int b = 0; b < NB; b++)
      if (cats[b] == t) wsi[o++] = b;
  }
  if (t == 0) {
    for (int s = 0; s < MAXG; s++) {
      wsi[132 + s * 4 + 0] = 0;
      wsi[132 + s * 4 + 1] = 0;
      wsi[132 + s * 4 + 2] = 0;
    }
    int rload[8];
    for (int r = 0; r < 8; r++) rload[r] = 0;
    for (int c = 0; c < NCAT; c++) {
      int n = cnt[c];
      if (n == 0) continue;
      int o = off[c];
      int r = 0;
      for (int k = 1; k < 8; k++) if (rload[k] < rload[r]) r = k;
      for (int j = 0; j < n; j += 4) {
        if (rload[r] >= 7) {
          r = 0;
          for (int k = 1; k < 8; k++) if (rload[k] < rload[r]) r = k;
        }
        int s = r + 8 * rload[r];
        rload[r]++;
        wsi[132 + s * 4 + 0] = c;
        wsi[132 + s * 4 + 1] = o + j;
        wsi[132 + s * 4 + 2] = (n - j) < 4 ? (n - j) : 4;
      }
    }
    wsi[128] = MAXG;
  }
}

// LAYER 1: Ain = x (fp32), A staged RAW fp32 via global_load_lds, cvt on read.
// LAYER 2: Ain = hidden (bf16), A staged bf16 via global_load_lds.
// B (W fp32) reg-staged 2 iterations ahead, packed to bf16 in LDS.
template <int LAYER>
__global__ __launch_bounds__(256)
void mlp_gemm(const void* __restrict__ Ain, const float* __restrict__ W,
              const float* __restrict__ bias, const int* __restrict__ wsi,
              void* __restrict__ Out, int K) {
  // XCD-aware remap: 16 column-blocks of one slot land on one XCD (L2 reuse).
  const int l    = blockIdx.y * 16 + blockIdx.x;   // gridDim.x == 16
  const int xcd  = l & 7;
  const int m    = l >> 3;                          // 0..111
  const int slot = xcd + 8 * (m >> 4);              // slot % 8 == xcd
  const int cat   = wsi[132 + slot * 4 + 0];
  const int start = wsi[132 + slot * 4 + 1];
  const int cnt   = wsi[132 + slot * 4 + 2];
  if (cnt == 0) return;
  const int n0 = (m & 15) * BN;

  // A tile raw: L1 = 128 rows x 32 fp32 (128 B/row); L2 = 128 rows x 32 bf16 (64 B/row)
  constexpr int ROWB   = (LAYER == 1) ? 128 : 64;       // bytes per A row in LDS
  constexpr int ABYTES = BM * ROWB;
  __shared__ __align__(16) unsigned char Asmem[2][ABYTES];
  __shared__ unsigned short Bs[2][4 * BN * 8];          // packed bf16 [kc][n][8k]

  const int tid  = threadIdx.x;
  const int lane = tid & 63;
  const int w    = tid >> 6;   // wave id 0..3  == local batch index for A rows

  const int wm  = (w >> 1) * 64;
  const int wn  = (w & 1) * 32;
  const int kg  = lane >> 4;    // 0..3
  const int kg2 = kg << 1;
  const int c16 = lane & 15;

  // ---- A DMA source: wave w stages rows w*32 .. w*32+31 (local batch w).
  // Global source pre-swizzled: logical chunk c of row r lives at physical
  // chunk c ^ (r & (NCH-1)); DMA dest is linear so we invert on the source.
  const int batchW = wsi[start + (w < cnt ? w : cnt - 1)];
  const float* alane1 = nullptr;
  const unsigned short* alane2 = nullptr;
  if constexpr (LAYER == 1) {
    const int r8 = lane >> 3, c8 = lane & 7;            // 8 rows/instr, 8 chunks/row
    alane1 = (const float*)Ain + ((size_t)batchW * TT + r8) * K + ((c8 ^ r8) << 2);
  } else {
    const int r4 = lane >> 2, c4 = lane & 3;            // 16 rows/instr, 4 chunks/row
    alane2 = (const unsigned short*)Ain + ((size_t)batchW * TT + r4) * K + ((c4 ^ (r4 & 3)) << 3);
  }

  auto dmaA = [&](int tile, int buf) {
    const int k0 = tile * BK;
    if constexpr (LAYER == 1) {
#pragma unroll
      for (int q = 0; q < 4; q++)   // q*8 rows; tok = q*8 + r8
        dma16(alane1 + (size_t)q * 8 * K + k0, &Asmem[buf][(w * 32 + q * 8) * 128]);
    } else {
#pragma unroll
      for (int q = 0; q < 2; q++)   // q*16 rows; tok = q*16 + r4
        dma16(alane2 + (size_t)q * 16 * K + k0, &Asmem[buf][(w * 32 + q * 16) * 64]);
    }
  };

  // ---- B staging: thread -> kc = w (k rows w*8..w*8+7), col = lane
  const float* Wcol = W + (size_t)cat * (size_t)K * 1024 + n0 + lane;
  auto loadB = [&](int tile, float br[8]) {
    const float* bp = Wcol + (size_t)(tile * BK + w * 8) * 1024;
#pragma unroll
    for (int r = 0; r < 8; r++) br[r] = bp[(size_t)r * 1024];
  };
  auto storeB = [&](int buf, const float br[8]) {
    uint4 bw = make_uint4(pk2bf(br[0], br[1]), pk2bf(br[2], br[3]),
                          pk2bf(br[4], br[5]), pk2bf(br[6], br[7]));
    *(uint4*)&Bs[buf][(w * BN + lane) * 8] = bw;
  };

  f32x4 acc[4][2];
#pragma unroll
  for (int i = 0; i < 4; i++)
#pragma unroll
    for (int j = 0; j < 2; j++) acc[i][j] = (f32x4){0.f, 0.f, 0.f, 0.f};

  auto compute = [&](int buf) {
    short8 afrag[4], bfrag[2];
    if constexpr (LAYER == 1) {
#pragma unroll
      for (int i = 0; i < 4; i++) {
        const int row = wm + i * 16 + c16;
        const float* rp = (const float*)&Asmem[buf][row * 128];
        const int sw = row & 7;
        float4 lo = *(const float4*)(rp + (((kg2 + 0) ^ sw) << 2));
        float4 hi = *(const float4*)(rp + (((kg2 + 1) ^ sw) << 2));
        uint4 u;
        u.x = cvtpk(lo.x, lo.y); u.y = cvtpk(lo.z, lo.w);
        u.z = cvtpk(hi.x, hi.y); u.w = cvtpk(hi.z, hi.w);
        afrag[i] = __builtin_bit_cast(short8, u);
      }
    } else {
#pragma unroll
      for (int i = 0; i < 4; i++) {
        const int row = wm + i * 16 + c16;
        const unsigned short* rp = (const unsigned short*)&Asmem[buf][row * 64];
        afrag[i] = *(const short8*)(rp + ((kg ^ (row & 3)) << 3));
      }
    }
#pragma unroll
    for (int j = 0; j < 2; j++)
      bfrag[j] = *(const short8*)&Bs[buf][(kg * BN + wn + j * 16 + c16) * 8];
#pragma unroll
    for (int i = 0; i < 4; i++)
#pragma unroll
      for (int j = 0; j < 2; j++)
        acc[i][j] = __builtin_amdgcn_mfma_f32_16x16x32_bf16(afrag[i], bfrag[j], acc[i][j], 0, 0, 0);
  };

  float brA[8], brB[8];
  const int nt = K / BK;   // 48 or 32 (even)

  // ---- prologue: DMA tile0 -> buf0; B(0)->brA; B(1)->brB; Bs[0] <- brA.
  dmaA(0, 0);
  __builtin_amdgcn_sched_barrier(0);     // keep DMA oldest in the vmcnt FIFO
  loadB(0, brA);
  loadB(1 < nt ? 1 : 0, brB);
  storeB(0, brA);                        // auto-counted vmcnt (retires DMA0+brA)
  asm volatile("s_waitcnt lgkmcnt(0)" ::: "memory");
  __builtin_amdgcn_s_barrier();

  for (int t = 0; t < nt; t += 2) {
    // ---- iter t (compute buf0): DMA A(t+1)->buf1, B(t+2)->brA, Bs[1]<-brB
    {
      const int tn = (t + 1 < nt) ? t + 1 : nt - 1;
      const int tb = (t + 2 < nt) ? t + 2 : nt - 1;
      dmaA(tn, 1);
      __builtin_amdgcn_sched_barrier(0);
      loadB(tb, brA);
      storeB(1, brB);                    // auto vmcnt(12): brB retired, DMA+brA in flight
      compute(0);
      asm volatile("s_waitcnt vmcnt(8) lgkmcnt(0)" ::: "memory");  // retire DMA, keep brA
      __builtin_amdgcn_s_barrier();
    }
    // ---- iter t+1 (compute buf1): DMA A(t+2)->buf0, B(t+3)->brB, Bs[0]<-brA
    {
      const int tn = (t + 2 < nt) ? t + 2 : nt - 1;
      const int tb = (t + 3 < nt) ? t + 3 : nt - 1;
      dmaA(tn, 0);
      __builtin_amdgcn_sched_barrier(0);
      loadB(tb, brB);
      storeB(0, brA);
      compute(1);
      asm volatile("s_waitcnt vmcnt(8) lgkmcnt(0)" ::: "memory");
      __builtin_amdgcn_s_barrier();
    }
  }

  // ---------- epilogue ----------
  const int rquad = (lane >> 4) * 4;
#pragma unroll
  for (int i = 0; i < 4; i++) {
#pragma unroll
    for (int j = 0; j < 2; j++) {
      int gcol = n0 + wn + j * 16 + c16;
      float bb = bias[cat * 1024 + gcol];
#pragma unroll
      for (int r = 0; r < 4; r++) {
        int lrow = wm + i * 16 + rquad + r;
        int lb2 = lrow >> 5;
        if (lb2 < cnt) {
          int b2 = wsi[start + lb2];
          long orow = (long)(b2 * TT + (lrow & 31));
          float v = acc[i][j][r] + bb;
          if constexpr (LAYER == 1) {
            v = fmaxf(v, 0.f);
            ((unsigned short*)Out)[orow * DMID + gcol] =
                __builtin_bit_cast(unsigned short, __float2bfloat16(v));
          } else {
            ((float*)Out)[orow * 1024 + gcol] = v;
          }
        }
      }
    }
  }
}

extern "C" void kernel_launch(void* const* d_in, const int* in_sizes, int n_in,
                              void* d_out, int out_size, void* d_ws, size_t ws_size,
                              hipStream_t stream) {
  const float* x       = (const float*)d_in[0];
  const int*   cat_ids = (const int*)d_in[1];
  const float* W1      = (const float*)d_in[2];
  const float* b1      = (const float*)d_in[3];
  const float* W2      = (const float*)d_in[4];
  const float* b2      = (const float*)d_in[5];
  float* out = (float*)d_out;

  int* wsi = (int*)d_ws;
  unsigned short* hidden = (unsigned short*)((char*)d_ws + 8192);

  build_groups<<<dim3(1), dim3(128), 0, stream>>>(cat_ids, wsi);
  mlp_gemm<1><<<dim3(1024 / BN, MAXG), dim3(256), 0, stream>>>(
      (const void*)x, W1, b1, wsi, (void*)hidden, DIN);
  mlp_gemm<2><<<dim3(1024 / BN, MAXG), dim3(256), 0, stream>>>(
      (const void*)hidden, W2, b2, wsi, (void*)out, DMID);
}